// Round 7
// baseline (416.061 us; speedup 1.0000x reference)
//
#include <hip/hip_runtime.h>

#define NN 50000
#define EE 1600000
#define D 128
#define SCAN_CHUNK 2048
#define SCAN_NB ((NN + SCAN_CHUNK - 1) / SCAN_CHUNK)   // 25
#define NSTR 50048
#define NODES_PER_BKT 6250     // 8 * 6250 = 50000 exact
#define NBLK_BIN ((EE + 2047) / 2048)                  // 782
#define SLICE_CAP 384          // Binomial(2048,1/8)=256±15; +8.5 sigma

typedef __attribute__((ext_vector_type(8))) short bf16x8;
typedef __attribute__((ext_vector_type(4))) float f32x4;

static __device__ __forceinline__ unsigned short f2bf(float f) {
  unsigned u = __float_as_uint(f);
  u += 0x7fffu + ((u >> 16) & 1u);   // RNE
  return (unsigned short)(u >> 16);
}
static __device__ __forceinline__ float bf2f(unsigned short s) {
  return __uint_as_float(((unsigned)s) << 16);
}

// ---------------- weight prep: Wt[col][k] bf16, 6 matrices ----------------
__global__ __launch_bounds__(256) void wt_prep(const float* __restrict__ ew1,
                                               const float* __restrict__ ew2,
                                               const float* __restrict__ cw,
                                               const float* __restrict__ dw1,
                                               const float* __restrict__ dw2,
                                               unsigned short* __restrict__ wt) {
  const int m = blockIdx.x;   // 0..5
  const float* W = (m == 0) ? ew1 : (m == 1) ? ew2 : (m == 2) ? cw
                 : (m == 3) ? (cw + 16384) : (m == 4) ? dw1 : dw2;
  unsigned short* o = wt + m * 16384;
  for (int i = threadIdx.x; i < 16384; i += 256) {
    const int col = i >> 7, k = i & 127;
    o[i] = f2bf(W[k * D + col]);    // o[col*128 + k]
  }
}

// ---------------- CSR build ----------------
// pass A: bin edges into per-(block,bucket) private FIFO slices. Wave-ballot
// aggregation -> 8 leader-only LDS atomics per 64-edge strip; NO barriers in
// the loop, NO global atomics, NO per-edge histogram.
__global__ __launch_bounds__(256) void bin_edges(const int* __restrict__ src,
                                                 const int* __restrict__ dst,
                                                 unsigned* __restrict__ fifo_s,
                                                 unsigned* __restrict__ fifo_d,
                                                 int* __restrict__ lcnt_g, int E) {
  __shared__ int lcnt[8];
  const int t = threadIdx.x;
  const int lane = t & 63, w = t >> 6;
  if (t < 8) lcnt[t] = 0;
  __syncthreads();
  const int blk = blockIdx.x;
  const int base = blk * 2048 + w * 512;
  #pragma unroll
  for (int it = 0; it < 8; ++it) {
    const int e = base + it * 64 + lane;
    int s = 0, d = 0, b = 8;
    if (e < E) {
      s = src[e];
      d = dst[e];
      b = (int)((unsigned)s / NODES_PER_BKT);
    }
    int slot = 0;
    #pragma unroll
    for (int bb = 0; bb < 8; ++bb) {
      const unsigned long long mask = __ballot(b == bb);
      if (mask) {   // wave-uniform
        const int leader = __builtin_ctzll(mask);
        int rbase = 0;
        if (lane == leader) rbase = atomicAdd(&lcnt[bb], __popcll(mask));
        rbase = __shfl(rbase, leader);
        if (b == bb) slot = rbase + (int)__popcll(mask & ((1ULL << lane) - 1ULL));
      }
    }
    if (b < 8) {
      const size_t o = ((size_t)blk * 8 + b) * SLICE_CAP + slot;
      fifo_s[o] = (unsigned)s;
      fifo_d[o] = (unsigned)d;
    }
  }
  __syncthreads();
  if (t < 8) lcnt_g[blk * 8 + t] = lcnt[t];
}

// pass B: bucket-local histogram. Bucket b blocks (blockIdx&7 -> XCD b) touch
// only cnt[6250b..6250(b+1)) = 25KB, XCD-L2-resident atomics.
__global__ __launch_bounds__(256) void hist_bucket(const unsigned* __restrict__ fifo_s,
                                                   const int* __restrict__ lcnt_g,
                                                   int* __restrict__ cnt, int nblk) {
  const int b = blockIdx.x & 7;
  const int step = gridDim.x >> 3;
  for (int blk = blockIdx.x >> 3; blk < nblk; blk += step) {
    const int m = lcnt_g[blk * 8 + b];
    const unsigned* f = fifo_s + ((size_t)blk * 8 + b) * SLICE_CAP;
    for (int i = threadIdx.x; i < m; i += 256)
      atomicAdd(&cnt[f[i]], 1);
  }
}

// --- hierarchical exclusive scan over cnt (200KB) ---
__global__ __launch_bounds__(256) void scan_partials(const int* __restrict__ cnt,
                                                     int* __restrict__ bsum, int n) {
  __shared__ int ws[4];
  const int t = threadIdx.x;
  const int base = blockIdx.x * SCAN_CHUNK + t * 8;
  int s = 0;
  #pragma unroll
  for (int k = 0; k < 8; ++k) {
    const int i = base + k;
    if (i < n) s += cnt[i];
  }
  #pragma unroll
  for (int d = 1; d < 64; d <<= 1) s += __shfl_xor(s, d);
  if ((t & 63) == 0) ws[t >> 6] = s;
  __syncthreads();
  if (t == 0) bsum[blockIdx.x] = ws[0] + ws[1] + ws[2] + ws[3];
}

__global__ __launch_bounds__(64) void scan_bases(const int* __restrict__ bsum,
                                                 int* __restrict__ bbase, int nb) {
  const int t = threadIdx.x;
  const int v = (t < nb) ? bsum[t] : 0;
  int x = v;
  #pragma unroll
  for (int d = 1; d < 64; d <<= 1) {
    int y = __shfl_up(x, (unsigned)d);
    if (t >= d) x += y;
  }
  if (t < nb) bbase[t] = x - v;
}

__global__ __launch_bounds__(256) void scan_apply(const int* __restrict__ cnt,
                                                  const int* __restrict__ bbase,
                                                  int* __restrict__ off, int n) {
  __shared__ int wpre[4];
  const int t = threadIdx.x;
  const int lane = t & 63, w = t >> 6;
  const int base = blockIdx.x * SCAN_CHUNK + t * 8;
  int v[8];
  int tot = 0;
  #pragma unroll
  for (int k = 0; k < 8; ++k) {
    const int i = base + k;
    v[k] = (i < n) ? cnt[i] : 0;
    tot += v[k];
  }
  int x = tot;
  #pragma unroll
  for (int d = 1; d < 64; d <<= 1) {
    int y = __shfl_up(x, (unsigned)d);
    if (lane >= d) x += y;
  }
  if (lane == 63) wpre[w] = x;
  __syncthreads();
  int wadd = 0;
  for (int ww = 0; ww < w; ++ww) wadd += wpre[ww];
  int pre = bbase[blockIdx.x] + wadd + (x - tot);
  #pragma unroll
  for (int k = 0; k < 8; ++k) {
    const int i = base + k;
    if (i < n) off[i] = pre;
    pre += v[k];
  }
}

// pass C: bucket-local fill. cur atomics XCD-local (25KB range); adj writes
// bucket-contained (single-XCD dirtying, proven low write-amp in R6).
__global__ __launch_bounds__(256) void fill_bucket(const unsigned* __restrict__ fifo_s,
                                                   const unsigned* __restrict__ fifo_d,
                                                   const int* __restrict__ lcnt_g,
                                                   const int* __restrict__ off,
                                                   int* __restrict__ cur,
                                                   int* __restrict__ adj, int nblk) {
  const int b = blockIdx.x & 7;
  const int step = gridDim.x >> 3;
  for (int blk = blockIdx.x >> 3; blk < nblk; blk += step) {
    const int m = lcnt_g[blk * 8 + b];
    const size_t so = ((size_t)blk * 8 + b) * SLICE_CAP;
    const unsigned* fs = fifo_s + so;
    const unsigned* fd = fifo_d + so;
    for (int i = threadIdx.x; i < m; i += 256) {
      const unsigned s = fs[i];
      const int p = off[s] + atomicAdd(&cur[s], 1);
      adj[p] = (int)fd[i];
    }
  }
}

// ---------------- MFMA linear layers (R4-verified) ----------
template<bool FUSED>
__global__ __launch_bounds__(256) void mfma_linear(const float* __restrict__ in,
                                                   const unsigned short* __restrict__ wt1,
                                                   const float* __restrict__ b1,
                                                   const unsigned short* __restrict__ wt2,
                                                   const float* __restrict__ b2,
                                                   void* __restrict__ outp, int n) {
  __shared__ unsigned short As[64 * 128];   // 16KB
  const int t = threadIdx.x;
  const int l = t & 63;
  const int w = t >> 6;
  const int rowBase = blockIdx.x * 64;

  { // stage in (f32) -> As (bf16, swizzled); coalesced float4 reads
    const int kg = t & 31;
    const int r0 = t >> 5;
    #pragma unroll
    for (int i = 0; i < 8; ++i) {
      const int r = r0 + i * 8;
      const int grow = rowBase + r;
      float4 v = make_float4(0.f, 0.f, 0.f, 0.f);
      if (grow < n) v = *(const float4*)(in + (size_t)grow * D + kg * 4);
      ushort4 pk = make_ushort4(f2bf(v.x), f2bf(v.y), f2bf(v.z), f2bf(v.w));
      *(ushort4*)((char*)As + r * 256 + ((kg * 8) ^ ((r & 7) << 4))) = pk;
    }
  }
  __syncthreads();

  const int wrow = w * 16;
  const int l16 = l & 15;
  const int lk = l >> 4;
  const int ar = wrow + l16;
  const int asw = (ar & 7) << 4;

  f32x4 acc[8];
  #pragma unroll
  for (int cf = 0; cf < 8; ++cf) acc[cf] = (f32x4){0.f, 0.f, 0.f, 0.f};
  #pragma unroll
  for (int ks = 0; ks < 4; ++ks) {
    const bf16x8 a = *(const bf16x8*)((char*)As + ar * 256 + ((ks * 64 + lk * 16) ^ asw));
    #pragma unroll
    for (int cf = 0; cf < 8; ++cf) {
      const bf16x8 b = *(const bf16x8*)(wt1 + (cf * 16 + l16) * D + ks * 32 + lk * 8);
      acc[cf] = __builtin_amdgcn_mfma_f32_16x16x32_bf16(a, b, acc[cf], 0, 0, 0);
    }
  }

  if (FUSED) {
    #pragma unroll
    for (int cf = 0; cf < 8; ++cf) {
      const int col = cf * 16 + l16;
      const float bb = b1[col];
      #pragma unroll
      for (int reg = 0; reg < 4; ++reg) {
        const int r = wrow + lk * 4 + reg;
        const float v = fmaxf(acc[cf][reg] + bb, 0.f);
        *(unsigned short*)((char*)As + r * 256 + ((col * 2) ^ ((r & 7) << 4))) = f2bf(v);
      }
    }
    f32x4 acc2[8];
    #pragma unroll
    for (int cf = 0; cf < 8; ++cf) acc2[cf] = (f32x4){0.f, 0.f, 0.f, 0.f};
    #pragma unroll
    for (int ks = 0; ks < 4; ++ks) {
      const bf16x8 a = *(const bf16x8*)((char*)As + ar * 256 + ((ks * 64 + lk * 16) ^ asw));
      #pragma unroll
      for (int cf = 0; cf < 8; ++cf) {
        const bf16x8 b = *(const bf16x8*)(wt2 + (cf * 16 + l16) * D + ks * 32 + lk * 8);
        acc2[cf] = __builtin_amdgcn_mfma_f32_16x16x32_bf16(a, b, acc2[cf], 0, 0, 0);
      }
    }
    float* out = (float*)outp;
    #pragma unroll
    for (int cf = 0; cf < 8; ++cf) {
      const int col = cf * 16 + l16;
      const float bb = b2[col];
      #pragma unroll
      for (int reg = 0; reg < 4; ++reg) {
        const int grow = rowBase + wrow + lk * 4 + reg;
        if (grow < n) out[(size_t)grow * D + col] = acc2[cf][reg] + bb;
      }
    }
  } else {
    unsigned short* out = (unsigned short*)outp;
    #pragma unroll
    for (int cf = 0; cf < 8; ++cf) {
      const int col = cf * 16 + l16;
      #pragma unroll
      for (int reg = 0; reg < 4; ++reg) {
        const int grow = rowBase + wrow + lk * 4 + reg;
        if (grow < n) out[(size_t)grow * D + col] = f2bf(acc[cf][reg]);
      }
    }
  }
}

// ---------------- fused gather-mean-relu-residual (bf16 g) ----------------
// 4 nodes per 256-thread block (1 wave/node), 8-deep gather unroll.
__global__ __launch_bounds__(256) void gather_update(const unsigned int* __restrict__ g,
                                                     float* __restrict__ h,
                                                     const int* __restrict__ adj,
                                                     const int* __restrict__ off,
                                                     const int* __restrict__ cnt,
                                                     const float* __restrict__ bias,
                                                     int n) {
  const int i = blockIdx.x * 4 + (threadIdx.x >> 6);
  if (i >= n) return;
  const int lane = threadIdx.x & 63;
  const int o = off[i];
  const int c = cnt[i];
  float ax[8] = {0.f, 0.f, 0.f, 0.f, 0.f, 0.f, 0.f, 0.f};
  float ay[8] = {0.f, 0.f, 0.f, 0.f, 0.f, 0.f, 0.f, 0.f};
  int e = 0;
  for (; e + 8 <= c; e += 8) {
    int j[8];
    #pragma unroll
    for (int k = 0; k < 8; ++k) j[k] = adj[o + e + k];
    #pragma unroll
    for (int k = 0; k < 8; ++k) {
      const unsigned v = g[(size_t)j[k] * 64 + lane];
      ax[k] += bf2f((unsigned short)(v & 0xffff));
      ay[k] += bf2f((unsigned short)(v >> 16));
    }
  }
  for (; e < c; ++e) {
    const int j = adj[o + e];
    const unsigned v = g[(size_t)j * 64 + lane];
    ax[0] += bf2f((unsigned short)(v & 0xffff));
    ay[0] += bf2f((unsigned short)(v >> 16));
  }
  const float sx = ((ax[0] + ax[1]) + (ax[2] + ax[3])) + ((ax[4] + ax[5]) + (ax[6] + ax[7]));
  const float sy = ((ay[0] + ay[1]) + (ay[2] + ay[3])) + ((ay[4] + ay[5]) + (ay[6] + ay[7]));
  const float inv = 1.0f / fmaxf((float)c, 1.0f);
  const float2 bb = ((const float2*)bias)[lane];
  float2 hv = ((float2*)h)[(size_t)i * 64 + lane];
  hv.x += fmaxf(sx * inv + bb.x, 0.f);
  hv.y += fmaxf(sy * inv + bb.y, 0.f);
  ((float2*)h)[(size_t)i * 64 + lane] = hv;
}

extern "C" void kernel_launch(void* const* d_in, const int* in_sizes, int n_in,
                              void* d_out, int out_size, void* d_ws, size_t ws_size,
                              hipStream_t stream) {
  const float* x   = (const float*)d_in[0];
  const int*   ei  = (const int*)d_in[1];
  const float* ew1 = (const float*)d_in[2];
  const float* eb1 = (const float*)d_in[3];
  const float* ew2 = (const float*)d_in[4];
  const float* eb2 = (const float*)d_in[5];
  const float* cw  = (const float*)d_in[6];
  const float* cb  = (const float*)d_in[7];
  const float* dw1 = (const float*)d_in[8];
  const float* db1 = (const float*)d_in[9];
  const float* dw2 = (const float*)d_in[10];
  const float* db2 = (const float*)d_in[11];

  const int n = NN, E = EE;

  // ws layout (~32.8 MB)
  float* h   = (float*)d_ws;                         // 6.4M f32
  int* cnt   = (int*)(h + (size_t)n * D);            // 50048
  int* cur   = cnt + NSTR;                           // 50048
  int* off   = cur + NSTR;                           // 50048
  int* bsum  = off + NSTR;                           // 64
  int* bbase = bsum + 64;                            // 64
  int* adj   = bbase + 64;                           // 1.6M
  unsigned short* wt = (unsigned short*)(adj + EE);  // 6*16384 bf16

  // d_out scratch (25.6MB): fifo_s 9.6MB | fifo_d 9.6MB | lcnt_g 25KB.
  // All dead before comm rounds reuse d_out[0..12.8MB) as bf16 g; decoder
  // finally overwrites d_out with the real f32 output.
  unsigned* fifo_s = (unsigned*)d_out;                       // 782*8*384
  unsigned* fifo_d = fifo_s + (size_t)NBLK_BIN * 8 * SLICE_CAP;
  int* lcnt_g      = (int*)(fifo_d + (size_t)NBLK_BIN * 8 * SLICE_CAP);
  unsigned short* g = (unsigned short*)d_out;

  const int* src = ei;
  const int* dst = ei + E;

  wt_prep<<<6, 256, 0, stream>>>(ew1, ew2, cw, dw1, dw2, wt);
  hipMemsetAsync(cnt, 0, 2 * NSTR * sizeof(int), stream);   // cnt + cur
  bin_edges<<<NBLK_BIN, 256, 0, stream>>>(src, dst, fifo_s, fifo_d, lcnt_g, E);
  hist_bucket<<<1024, 256, 0, stream>>>(fifo_s, lcnt_g, cnt, NBLK_BIN);
  scan_partials<<<SCAN_NB, 256, 0, stream>>>(cnt, bsum, n);
  scan_bases<<<1, 64, 0, stream>>>(bsum, bbase, SCAN_NB);
  scan_apply<<<SCAN_NB, 256, 0, stream>>>(cnt, bbase, off, n);
  fill_bucket<<<1024, 256, 0, stream>>>(fifo_s, fifo_d, lcnt_g, off, cur, adj, NBLK_BIN);

  const int gb = (n + 63) / 64;   // 782

  // encoder (fused pair): x -> h
  mfma_linear<true><<<gb, 256, 0, stream>>>(x, wt, eb1, wt + 16384, eb2, h, n);
  // communication rounds: g = h @ cw[r] (bf16); h += relu(mean(g[adj]) + cb[r])
  for (int r = 0; r < 2; ++r) {
    mfma_linear<false><<<gb, 256, 0, stream>>>(h, wt + (2 + r) * 16384,
                                               nullptr, nullptr, nullptr, g, n);
    gather_update<<<(n + 3) / 4, 256, 0, stream>>>((const unsigned int*)g, h, adj,
                                                   off, cnt, cb + r * D, n);
  }
  // decoder (fused pair): h -> d_out (f32, direct)
  mfma_linear<true><<<gb, 256, 0, stream>>>(h, wt + 4 * 16384, db1,
                                            wt + 5 * 16384, db2, d_out, n);
}